// Round 14
// baseline (114.165 us; speedup 1.0000x reference)
//
#include <hip/hip_runtime.h>
#include <stdint.h>

#define NUM_B 2
#define SEQ 2048
#define DMODEL 768
#define NHEAD 12
#define DK 64
#define MROWS (NUM_B * SEQ) /* 4096 */
#define BHS (NUM_B * NHEAD * SEQ) /* 49152 */

typedef __attribute__((ext_vector_type(4))) float f32x4;
typedef __attribute__((ext_vector_type(16))) float f32x16;
typedef __attribute__((ext_vector_type(8))) short bf16x8; // MFMA A/B frag (8 bf16)
typedef __attribute__((ext_vector_type(8))) unsigned short us8;
typedef __attribute__((ext_vector_type(4))) unsigned short us4;
typedef __attribute__((ext_vector_type(4))) unsigned int u32x4;
typedef unsigned short u16;
typedef unsigned int u32;
typedef unsigned long long u64;

__device__ __forceinline__ u16 to_bf16(float f) {
  u32 u = __builtin_bit_cast(u32, f);
  u += 0x7FFFu + ((u >> 16) & 1u); // RNE
  return (u16)(u >> 16);
}

__device__ __forceinline__ float bf16_to_f32(u16 u) {
  return __builtin_bit_cast(float, ((u32)u) << 16);
}

__device__ __forceinline__ u32 cvt_pk_bf16(float lo, float hi) {
  u32 r;
  asm("v_cvt_pk_bf16_f32 %0, %1, %2" : "=v"(r) : "v"(lo), "v"(hi));
  return r;
}

// raw HW exp2 (single trans instr; avoids OCML wrapper). Inputs bounded here.
__device__ __forceinline__ float fexp2(float x) {
  float r;
  asm("v_exp_f32 %0, %1" : "=v"(r) : "v"(x));
  return r;
}

// sign-extended 1-bit field extract: returns 0 or -1
__device__ __forceinline__ int sext_bit(u32 src, int pos) {
#if __has_builtin(__builtin_amdgcn_sbfe)
  return __builtin_amdgcn_sbfe((int)src, pos, 1);
#else
  return ((int)(src << (31 - pos))) >> 31;
#endif
}

// async global->LDS, 16B per lane; LDS dest must be wave-uniform base (+lane*16)
__device__ __forceinline__ void gload_lds16(const u16* g, u16* l) {
#pragma clang diagnostic push
#pragma clang diagnostic ignored "-Waddress-space-conversion"
  __builtin_amdgcn_global_load_lds((const __attribute__((address_space(1))) u32*)g,
                                   (__attribute__((address_space(3))) u32*)l, 16, 0, 0);
#pragma clang diagnostic pop
}

// ---------------- f32 -> bf16 convert only (mask pack moved to proj dispatch) ----------------
__global__ void cvt_pack(const float* s0, const float* s1, const float* s2,
                         const float* s3, const float* s4, const float* s5,
                         u16* d0, u16* d1, u16* d2, u16* d3, u16* d4, u16* d5,
                         int nbig, int nsmall) {
  int y = blockIdx.y;
  const float* src; u16* dst; int n8;
  if (y == 0)      { src = s0; dst = d0; n8 = nbig; }
  else if (y == 1) { src = s1; dst = d1; n8 = nbig; }
  else if (y == 2) { src = s2; dst = d2; n8 = nbig; }
  else if (y == 3) { src = s3; dst = d3; n8 = nsmall; }
  else if (y == 4) { src = s4; dst = d4; n8 = nsmall; }
  else             { src = s5; dst = d5; n8 = nsmall; }
  int i = blockIdx.x * blockDim.x + threadIdx.x;
  if (i >= n8) return;
  const f32x4* p = reinterpret_cast<const f32x4*>(src) + (size_t)i * 2;
  f32x4 lo = p[0], hi = p[1];
  us8 r;
  r[0] = to_bf16(lo[0]); r[1] = to_bf16(lo[1]); r[2] = to_bf16(lo[2]); r[3] = to_bf16(lo[3]);
  r[4] = to_bf16(hi[0]); r[5] = to_bf16(hi[1]); r[6] = to_bf16(hi[2]); r[7] = to_bf16(hi[3]);
  *(reinterpret_cast<us8*>(dst) + i) = r;
}

// ---------------- projection GEMM (y<3) + mask bit-pack (y==3, co-scheduled) ----------------
// GEMM: 128x64 tiles, out = X @ W^T + bias, LINEAR [4096][768] bf16; y==0 folds
// (1/8)*log2(e). Mask blocks are pure-memory and hide under the MFMA blocks.
__global__ __launch_bounds__(256) void proj_gemm(
    const u16* __restrict__ X0, const u16* __restrict__ X1, const u16* __restrict__ X2,
    const u16* __restrict__ W0, const u16* __restrict__ W1, const u16* __restrict__ W2,
    const float* __restrict__ b0, const float* __restrict__ b1, const float* __restrict__ b2,
    const int* __restrict__ mask, u64* __restrict__ bits,
    u16* __restrict__ o0, u16* __restrict__ o1, u16* __restrict__ o2) {
  if (blockIdx.y == 3) {
    // mask pack: 384 blocks x 86 iters x 256 thr >= B*S*S ints (bounds-checked)
    int tid = threadIdx.x;
#pragma unroll
    for (int it = 0; it < 86; ++it) {
      int i = (it * 384 + blockIdx.x) * 256 + tid;
      if (i < NUM_B * SEQ * SEQ) {
        u64 bm = __ballot(mask[i] != 0);
        if ((tid & 63) == 0) {
          int word = (i >> 6) & 31;
          int s = (i >> 11) & 2047;
          int b = i >> 22;
          bits[((size_t)b * 32 + word) * 2048 + s] = bm;
        }
      }
    }
    return;
  }

  __shared__ u16 As[2][8192];   // [buf][128 rows][64 k] swizzled
  __shared__ u16 Bs[2][4096];   // [buf][64 rows][64 k] swizzled

  int lin = blockIdx.x + 384 * blockIdx.y;          // 0..1151
  int wid = (lin & 7) * 144 + (lin >> 3);           // XCD-contiguous remap (1152%8==0)
  int y = wid / 384;
  int r384 = wid % 384;
  int bm = r384 / 12, bn = r384 % 12;

  const u16* X; const u16* W; const float* bias; u16* out;
  if (y == 0)      { X = X0; W = W0; bias = b0; out = o0; }
  else if (y == 1) { X = X1; W = W1; bias = b1; out = o1; }
  else             { X = X2; W = W2; bias = b2; out = o2; }
  float osc = (y == 0) ? 0.18033688011112042f : 1.0f;

  int tid = threadIdx.x, w = tid >> 6, l = tid & 63;
  int g = l >> 4, c = l & 15;
  int m0 = bm * 128, n0 = bn * 64;
  int wm = w >> 1, wn = w & 1;      // wave tile: 64 rows x 32 cols

  int srow = l >> 3;            // 0..7
  int cg = (l & 7) ^ srow;      // pre-swizzled source chunk

  f32x4 acc[4][2] = {};

  auto stage = [&](int kt, int buf) {
    int k0 = kt * 64;
#pragma unroll
    for (int i = 0; i < 4; ++i) {
      int row = i * 32 + w * 8 + srow;
      gload_lds16(X + (size_t)(m0 + row) * DMODEL + k0 + cg * 8, &As[buf][(i * 256 + w * 64) * 8]);
    }
#pragma unroll
    for (int i = 0; i < 2; ++i) {
      int row = i * 32 + w * 8 + srow;
      gload_lds16(W + (size_t)(n0 + row) * DMODEL + k0 + cg * 8, &Bs[buf][(i * 256 + w * 64) * 8]);
    }
  };

  stage(0, 0);
  __syncthreads();

  for (int kt = 0; kt < 12; ++kt) {
    int cur = kt & 1;
    if (kt < 11) stage(kt + 1, cur ^ 1);
#pragma unroll
    for (int kk = 0; kk < 2; ++kk) {
      bf16x8 av[4], bv[2];
#pragma unroll
      for (int m = 0; m < 4; ++m) {
        int row = wm * 64 + m * 16 + c;
        av[m] = *(const bf16x8*)&As[cur][row * 64 + ((kk * 32 + g * 8) ^ ((row & 7) << 3))];
      }
#pragma unroll
      for (int n = 0; n < 2; ++n) {
        int row = wn * 32 + n * 16 + c;
        bv[n] = *(const bf16x8*)&Bs[cur][row * 64 + ((kk * 32 + g * 8) ^ ((row & 7) << 3))];
      }
#pragma unroll
      for (int m = 0; m < 4; ++m)
#pragma unroll
        for (int n = 0; n < 2; ++n)
          acc[m][n] = __builtin_amdgcn_mfma_f32_16x16x32_bf16(av[m], bv[n], acc[m][n], 0, 0, 0);
    }
    __syncthreads();
  }
  // epilogue: C/D layout col=lane&15, row=(lane>>4)*4+reg
#pragma unroll
  for (int n = 0; n < 2; ++n) {
    int gcol = n0 + wn * 32 + n * 16 + c;
    float bvv = bias[gcol];
#pragma unroll
    for (int m = 0; m < 4; ++m) {
      int grow0 = m0 + wm * 64 + m * 16 + g * 4;
#pragma unroll
      for (int r = 0; r < 4; ++r)
        out[(size_t)(grow0 + r) * DMODEL + gcol] = to_bf16((acc[m][n][r] + bvv) * osc);
    }
  }
}

// ---------------- V transpose: vh[(bh*2048+s')][64 d] -> vhT[(bh*64+d)][2048 s'] ----------------
__global__ __launch_bounds__(256) void transposeV(const u16* __restrict__ vh,
                                                  u16* __restrict__ vhT) {
  __shared__ u16 T[64][72];   // [d][s' local]
  int bh = blockIdx.y;        // 0..23
  int s0 = blockIdx.x * 64;
  int tid = threadIdx.x;
#pragma unroll
  for (int it = 0; it < 2; ++it) {
    int cch = it * 256 + tid;
    int r = cch >> 3, dc = (cch & 7) * 8;     // s'-row r, d-chunk dc
    us8 v = *(const us8*)(vh + ((size_t)bh * 2048 + s0 + r) * 64 + dc);
#pragma unroll
    for (int j = 0; j < 8; ++j) T[dc + j][r] = v[j];   // scatter-transpose into LDS
  }
  __syncthreads();
#pragma unroll
  for (int it = 0; it < 2; ++it) {
    int cch = it * 256 + tid;
    int d = cch >> 3, sc = (cch & 7) * 8;
    us8 v = *(const us8*)&T[d][sc];
    *(us8*)(vhT + ((size_t)bh * 64 + d) * 2048 + s0 + sc) = v;
  }
}

// ---------------- fused flash attention: swapped 32x32 QK^T, fixed-m softmax, KV-split=4 ----------------
// grid (16,12,8) remapped; per block 4 waves x 32 q-rows = 128 q, 512-key strip.
// Sequential 32-key half-tiles (one f32x16 score block live; VGPR 88).
// NO s_setprio: 4-wave barrier-synced lockstep structure — T5/m190 shows setprio
// starves co-resident waves' VALU in lockstep schedules (only helps role-split ones).
// Per-strip output NORMALIZED (O_s/l_s): strip0 -> f32 po0 (d_out), strips 1-3 -> bf16.
__global__ __launch_bounds__(256) void attn32(
    const u16* __restrict__ qh, const u16* __restrict__ kh, const u16* __restrict__ vt,
    const u64* __restrict__ mbt, float* __restrict__ po0, u16* __restrict__ po1,
    u16* __restrict__ po2, u16* __restrict__ po3, float* __restrict__ pl) {
  __shared__ u16 K0[4096], V0[4096], K1[4096], V1[4096];

  int tid = threadIdx.x, w = tid >> 6, l = tid & 63;
  int q = l & 31, hi = l >> 5;

  int lin = blockIdx.x + 16 * (blockIdx.y + 12 * blockIdx.z);
  int wid = (lin & 7) * 192 + (lin >> 3);           // 1536 % 8 == 0, bijective
  int qb = wid & 15;
  int rest = wid >> 4;
  int h = rest % 12;
  int z = rest / 12;                                // 0..7
  int strip = z & 3, b = z >> 2;
  int kbase = strip * 512;
  size_t hb = (size_t)(b * NHEAD + h) * SEQ * DK;
  int qrow = qb * 128 + w * 32 + q;

  // Q as B-operand: col=lane&31=q, k = (lane>>5)*8 + j within each 16-slice
  bf16x8 qf[4];
#pragma unroll
  for (int s = 0; s < 4; ++s)
    qf[s] = *(const bf16x8*)(qh + hb + (size_t)qrow * DK + s * 16 + hi * 8);

  f32x16 o0 = {}, o1 = {};
  float l_run = 0.f;

  // staging source pointers (per-lane, pre-swizzled)
  int idx0 = w * 64 + l;                 // chunk 0..255
  int r0s = idx0 >> 3;                   // source row 0..31
  int sc0 = ((idx0 & 7) ^ (r0s & 7)) * 8;
  const u16* kS = kh + hb + (size_t)(kbase + r0s) * DK + sc0;
  const u16* vS = vt + hb + (size_t)r0s * SEQ + kbase + sc0;
  const u64* mp = mbt + ((size_t)b * 32 + strip * 8) * SEQ + qrow;

  auto stage = [&](int t, u16* Kd, u16* Vd) {
    const u16* kp = kS + (size_t)t * (64 * DK);
    const u16* vp = vS + t * 64;
    gload_lds16(kp,            Kd + w * 512);
    gload_lds16(kp + 32 * DK,  Kd + 2048 + w * 512);
    gload_lds16(vp,            Vd + w * 512);
    gload_lds16(vp + 32 * SEQ, Vd + 2048 + w * 512);
  };

  // hoisted swizzled LDS read offsets (u16 units); rows q and q+32 share the slot
  int ofA[4];
#pragma unroll
  for (int s = 0; s < 4; ++s)
    ofA[s] = q * 64 + (((2 * s + hi) ^ (q & 7)) * 8);

  // one 32-key half-tile: QK^T -> exp/mask -> l partials -> pack -> PV
  auto computeHalf = [&](const u16* Kc, const u16* Vc, u32 mm, int kb) {
    const int roff = kb * 2048;          // K rows q+32 for the upper half
    f32x16 s = {};
#pragma unroll
    for (int ss = 0; ss < 4; ++ss) {
      bf16x8 kf = *(const bf16x8*)(Kc + ofA[ss] + roff);
      s = __builtin_amdgcn_mfma_f32_32x32x16_bf16(kf, qf[ss], s, 0, 0, 0);
    }

    // raw v_exp_f32 + 2-op mask; 4-chain partial row-sums feed l_run (VALU)
    float rs0 = 0.f, rs1 = 0.f, rs2 = 0.f, rs3 = 0.f;
#pragma unroll
    for (int r = 0; r < 16; ++r) {
      const int p = (r & 3) + 8 * (r >> 2);      // relative bit pos for this reg
      float e = fexp2(s[r]);
      int km = sext_bit(mm, p);                  // 0 / ~0
      e = __builtin_bit_cast(float, __builtin_bit_cast(int, e) & km);
      s[r] = e;
      if ((r & 3) == 0) rs0 += e;
      else if ((r & 3) == 1) rs1 += e;
      else if ((r & 3) == 2) rs2 += e;
      else rs3 += e;
    }
    l_run += (rs0 + rs1) + (rs2 + rs3);

    // pack P to bf16 A-frags; cross-half exchange via permlane32_swap.
    // (vdst=A, vsrc=B): A' = [A.row0|B.row0] (word0), B' = [A.row1|B.row1] (word2).
#pragma unroll
    for (int hf = 0; hf < 2; ++hf) {
      int ks = kb * 2 + hf;
      u32 A0 = cvt_pk_bf16(s[8 * hf + 0], s[8 * hf + 1]);
      u32 A1 = cvt_pk_bf16(s[8 * hf + 2], s[8 * hf + 3]);
      u32 B0 = cvt_pk_bf16(s[8 * hf + 4], s[8 * hf + 5]);
      u32 B1 = cvt_pk_bf16(s[8 * hf + 6], s[8 * hf + 7]);
      asm("v_permlane32_swap_b32 %0, %1" : "+v"(A0), "+v"(B0));
      asm("v_permlane32_swap_b32 %0, %1" : "+v"(A1), "+v"(B1));
      u32x4 fw;
      fw[0] = A0; fw[1] = A1; fw[2] = B0; fw[3] = B1;
      bf16x8 pa = __builtin_bit_cast(bf16x8, fw);
      bf16x8 v0 = *(const bf16x8*)(Vc + ofA[ks]);
      bf16x8 v1 = *(const bf16x8*)(Vc + ofA[ks] + 2048);
      o0 = __builtin_amdgcn_mfma_f32_32x32x16_bf16(pa, v0, o0, 0, 0, 0);
      o1 = __builtin_amdgcn_mfma_f32_32x32x16_bf16(pa, v1, o1, 0, 0, 0);
    }
  };

  auto compute = [&](const u16* Kc, const u16* Vc, u64 mcur) {
    computeHalf(Kc, Vc, (u32)(mcur >> (4 * hi)), 0);
    computeHalf(Kc, Vc, (u32)((mcur >> 32) >> (4 * hi)), 1);
  };

  // ---- software-pipelined main loop over 8 tiles, unroll-2 with named buffers ----
  stage(0, K0, V0);
  u64 mcur = mp[0];
  __syncthreads();

  for (int tt = 0; tt < 4; ++tt) {
    const int t0 = 2 * tt;
    u64 mnext = mp[(size_t)(t0 + 1) * SEQ];
    stage(t0 + 1, K1, V1);          // in flight across this compute
    compute(K0, V0, mcur);
    __syncthreads();                // drains stage(t0+1)
    mcur = mnext;
    if (tt < 3) {
      mnext = mp[(size_t)(t0 + 2) * SEQ];
      stage(t0 + 2, K0, V0);
    }
    compute(K1, V1, mcur);
    __syncthreads();
    mcur = mnext;
  }

  // ---- epilogue: cross-half l reduce; lane j holds l(row j&31); per-row via shfl
  l_run += __shfl_xor(l_run, 32);
  if (strip == 0) {
#pragma unroll
    for (int r = 0; r < 16; ++r) {
      int crow = (r & 3) + 8 * (r >> 2) + 4 * hi;
      float invl = __builtin_amdgcn_rcpf(__shfl(l_run, crow));
      int row = qb * 128 + w * 32 + crow;
      po0[hb + (size_t)row * DK + q]      = o0[r] * invl;
      po0[hb + (size_t)row * DK + 32 + q] = o1[r] * invl;
    }
  } else {
    u16* oo = (strip == 1) ? po1 : (strip == 2) ? po2 : po3;
#pragma unroll
    for (int r = 0; r < 16; ++r) {
      int crow = (r & 3) + 8 * (r >> 2) + 4 * hi;
      float invl = __builtin_amdgcn_rcpf(__shfl(l_run, crow));
      int row = qb * 128 + w * 32 + crow;
      oo[hb + (size_t)row * DK + q]      = to_bf16(o0[r] * invl);
      oo[hb + (size_t)row * DK + 32 + q] = to_bf16(o1[r] * invl);
    }
  }
  if (hi == 0)
    pl[(size_t)strip * BHS + (size_t)(b * NHEAD + h) * SEQ + qrow] = l_run;
}

// ---------------- combine the 4 normalized KV-strip partials (l-weighted avg) ----------------
__global__ __launch_bounds__(256) void combine_kernel(
    const float* __restrict__ po0, const u16* __restrict__ po1,
    const u16* __restrict__ po2, const u16* __restrict__ po3,
    const float* __restrict__ pl, float* __restrict__ out) {
  int i = blockIdx.x * 256 + threadIdx.x;     // vec4 index; grid covers BHS*16 exactly
  int row = i >> 4;
  float l0 = pl[row], l1 = pl[BHS + row], l2 = pl[2 * BHS + row], l3 = pl[3 * BHS + row];
  float inv = 1.f / (l0 + l1 + l2 + l3);
  f32x4 a = ((const f32x4*)po0)[i];
  us4 b1 = ((const us4*)po1)[i];
  us4 b2 = ((const us4*)po2)[i];
  us4 b3 = ((const us4*)po3)[i];
  f32x4 acc;
#pragma unroll
  for (int j = 0; j < 4; ++j)
    acc[j] = a[j] * l0 + bf16_to_f32(b1[j]) * l1 + bf16_to_f32(b2[j]) * l2 +
             bf16_to_f32(b3[j]) * l3;
  ((f32x4*)out)[i] = acc * inv;   // po0 == out: in-place per-element, safe
}

extern "C" void kernel_launch(void* const* d_in, const int* in_sizes, int n_in,
                              void* d_out, int out_size, void* d_ws, size_t ws_size,
                              hipStream_t stream) {
  const float* q    = (const float*)d_in[0];
  const float* k    = (const float*)d_in[1];
  const float* v    = (const float*)d_in[2];
  const int*   mask = (const int*)d_in[3];
  const float* Wq   = (const float*)d_in[4];
  const float* bq   = (const float*)d_in[5];
  const float* Wk   = (const float*)d_in[6];
  const float* bk   = (const float*)d_in[7];
  const float* Wv   = (const float*)d_in[8];
  const float* bv   = (const float*)d_in[9];

  char* ws = (char*)d_ws;
  const size_t szX = (size_t)MROWS * DMODEL * 2;   // 6291456 B
  const size_t szW = (size_t)DMODEL * DMODEL * 2;  // 1179648 B
  u16* xq  = (u16*)(ws);
  u16* xk  = (u16*)(ws + szX);
  u16* xv  = (u16*)(ws + 2 * szX);
  u16* wqb = (u16*)(ws + 3 * szX);
  u16* wkb = (u16*)(ws + 3 * szX + szW);
  u16* wvb = (u16*)(ws + 3 * szX + 2 * szW);
  u16* qh  = (u16*)(ws + 3 * szX + 3 * szW);
  u16* kh  = (u16*)(ws + 4 * szX + 3 * szW);
  u16* vh  = (u16*)(ws + 5 * szX + 3 * szW);       // linear [4096][768] == [bh][s'][d]
  u64* mb  = (u64*)(ws + 6 * szX + 3 * szW);       // 1 MB, [b][word][s]

  // dead-after-proj/transpose regions reused during attention:
  u16*   po1b = (u16*)(ws);                         // xq slot (6.29 MB, bf16 partial)
  u16*   po2b = (u16*)(ws + szX);                   // xk slot
  u16*   vhT  = (u16*)(ws + 2 * szX);               // xv slot (written by transposeV)
  float* pl   = (float*)(ws + 3 * szX);             // weights slot (4*BHS*4 = 786 KB)
  u16*   po3b = (u16*)(ws + 5 * szX + 3 * szW);     // vh slot (dead after transposeV)
  float* po0  = (float*)d_out;

  const int nbig = (MROWS * DMODEL) / 8;    // 393216
  const int nsmall = (DMODEL * DMODEL) / 8; // 73728

  cvt_pack<<<dim3(1536, 6), 256, 0, stream>>>(q, k, v, Wq, Wk, Wv,
                                              xq, xk, xv, wqb, wkb, wvb, nbig, nsmall);
  proj_gemm<<<dim3(384, 4), 256, 0, stream>>>(
      xq, xk, xv, wqb, wkb, wvb, bq, bk, bv, mask, mb, qh, kh, vh);
  transposeV<<<dim3(32, 24), 256, 0, stream>>>(vh, vhT);
  attn32<<<dim3(16, 12, 8), 256, 0, stream>>>(qh, kh, vhT, mb, po0, po1b, po2b, po3b, pl);
  combine_kernel<<<(BHS * 16) / 256, 256, 0, stream>>>(po0, po1b, po2b, po3b, pl, (float*)d_out);
}

// Round 15
// 102.417 us; speedup vs baseline: 1.1147x; 1.1147x over previous
//
#include <hip/hip_runtime.h>
#include <stdint.h>

#define NUM_B 2
#define SEQ 2048
#define DMODEL 768
#define NHEAD 12
#define DK 64
#define MROWS (NUM_B * SEQ) /* 4096 */
#define BHS (NUM_B * NHEAD * SEQ) /* 49152 */

typedef __attribute__((ext_vector_type(4))) float f32x4;
typedef __attribute__((ext_vector_type(16))) float f32x16;
typedef __attribute__((ext_vector_type(8))) short bf16x8; // MFMA A/B frag (8 bf16)
typedef __attribute__((ext_vector_type(8))) unsigned short us8;
typedef __attribute__((ext_vector_type(4))) unsigned short us4;
typedef __attribute__((ext_vector_type(4))) unsigned int u32x4;
typedef unsigned short u16;
typedef unsigned int u32;
typedef unsigned long long u64;

__device__ __forceinline__ u16 to_bf16(float f) {
  u32 u = __builtin_bit_cast(u32, f);
  u += 0x7FFFu + ((u >> 16) & 1u); // RNE
  return (u16)(u >> 16);
}

__device__ __forceinline__ float bf16_to_f32(u16 u) {
  return __builtin_bit_cast(float, ((u32)u) << 16);
}

__device__ __forceinline__ u32 cvt_pk_bf16(float lo, float hi) {
  u32 r;
  asm("v_cvt_pk_bf16_f32 %0, %1, %2" : "=v"(r) : "v"(lo), "v"(hi));
  return r;
}

// raw HW exp2 (single trans instr; avoids OCML wrapper). Inputs bounded here.
__device__ __forceinline__ float fexp2(float x) {
  float r;
  asm("v_exp_f32 %0, %1" : "=v"(r) : "v"(x));
  return r;
}

// sign-extended 1-bit field extract: returns 0 or -1
__device__ __forceinline__ int sext_bit(u32 src, int pos) {
#if __has_builtin(__builtin_amdgcn_sbfe)
  return __builtin_amdgcn_sbfe((int)src, pos, 1);
#else
  return ((int)(src << (31 - pos))) >> 31;
#endif
}

// async global->LDS, 16B per lane; LDS dest must be wave-uniform base (+lane*16)
__device__ __forceinline__ void gload_lds16(const u16* g, u16* l) {
#pragma clang diagnostic push
#pragma clang diagnostic ignored "-Waddress-space-conversion"
  __builtin_amdgcn_global_load_lds((const __attribute__((address_space(1))) u32*)g,
                                   (__attribute__((address_space(3))) u32*)l, 16, 0, 0);
#pragma clang diagnostic pop
}

// ---------------- fused f32->bf16 convert (y<6) + mask bit-pack (y==6) ----------------
__global__ void cvt_pack(const float* s0, const float* s1, const float* s2,
                         const float* s3, const float* s4, const float* s5,
                         const int* __restrict__ mask,
                         u16* d0, u16* d1, u16* d2, u16* d3, u16* d4, u16* d5,
                         u64* __restrict__ bits, int nbig, int nsmall) {
  int y = blockIdx.y;
  if (y == 6) {
    // pack: 2048 blocks x 16 iters x 256 threads = exactly B*S*S ints
    int base = blockIdx.x * (16 * 256) + threadIdx.x;
#pragma unroll
    for (int it = 0; it < 16; ++it) {
      int i = base + it * 256;
      u64 bm = __ballot(mask[i] != 0);
      if ((threadIdx.x & 63) == 0) {
        int word = (i >> 6) & 31;
        int s = (i >> 11) & 2047;
        int b = i >> 22;
        bits[((size_t)b * 32 + word) * 2048 + s] = bm;
      }
    }
    return;
  }
  const float* src; u16* dst; int n8;
  if (y == 0)      { src = s0; dst = d0; n8 = nbig; }
  else if (y == 1) { src = s1; dst = d1; n8 = nbig; }
  else if (y == 2) { src = s2; dst = d2; n8 = nbig; }
  else if (y == 3) { src = s3; dst = d3; n8 = nsmall; }
  else if (y == 4) { src = s4; dst = d4; n8 = nsmall; }
  else             { src = s5; dst = d5; n8 = nsmall; }
  int i = blockIdx.x * blockDim.x + threadIdx.x;
  if (i >= n8) return;
  const f32x4* p = reinterpret_cast<const f32x4*>(src) + (size_t)i * 2;
  f32x4 lo = p[0], hi = p[1];
  us8 r;
  r[0] = to_bf16(lo[0]); r[1] = to_bf16(lo[1]); r[2] = to_bf16(lo[2]); r[3] = to_bf16(lo[3]);
  r[4] = to_bf16(hi[0]); r[5] = to_bf16(hi[1]); r[6] = to_bf16(hi[2]); r[7] = to_bf16(hi[3]);
  *(reinterpret_cast<us8*>(dst) + i) = r;
}

// ---------------- projection GEMM: out = X @ W^T + bias, 2-phase dbuf ----------------
// 128x64 tiles (1152 blocks, LDS 48KB -> 3 resident). All outputs LINEAR [4096][768]
// bf16. y==0 (Q) folds (1/8)*log2(e) into the output.
__global__ __launch_bounds__(256) void proj_gemm(
    const u16* __restrict__ X0, const u16* __restrict__ X1, const u16* __restrict__ X2,
    const u16* __restrict__ W0, const u16* __restrict__ W1, const u16* __restrict__ W2,
    const float* __restrict__ b0, const float* __restrict__ b1, const float* __restrict__ b2,
    u16* __restrict__ o0, u16* __restrict__ o1, u16* __restrict__ o2) {
  __shared__ u16 As[2][8192];   // [buf][128 rows][64 k] swizzled
  __shared__ u16 Bs[2][4096];   // [buf][64 rows][64 k] swizzled

  int lin = blockIdx.x + 384 * blockIdx.y;          // 0..1151
  int wid = (lin & 7) * 144 + (lin >> 3);           // XCD-contiguous remap (1152%8==0)
  int y = wid / 384;
  int r384 = wid % 384;
  int bm = r384 / 12, bn = r384 % 12;

  const u16* X; const u16* W; const float* bias; u16* out;
  if (y == 0)      { X = X0; W = W0; bias = b0; out = o0; }
  else if (y == 1) { X = X1; W = W1; bias = b1; out = o1; }
  else             { X = X2; W = W2; bias = b2; out = o2; }
  float osc = (y == 0) ? 0.18033688011112042f : 1.0f;

  int tid = threadIdx.x, w = tid >> 6, l = tid & 63;
  int g = l >> 4, c = l & 15;
  int m0 = bm * 128, n0 = bn * 64;
  int wm = w >> 1, wn = w & 1;      // wave tile: 64 rows x 32 cols

  int srow = l >> 3;            // 0..7
  int cg = (l & 7) ^ srow;      // pre-swizzled source chunk

  f32x4 acc[4][2] = {};

  auto stage = [&](int kt, int buf) {
    int k0 = kt * 64;
#pragma unroll
    for (int i = 0; i < 4; ++i) {
      int row = i * 32 + w * 8 + srow;
      gload_lds16(X + (size_t)(m0 + row) * DMODEL + k0 + cg * 8, &As[buf][(i * 256 + w * 64) * 8]);
    }
#pragma unroll
    for (int i = 0; i < 2; ++i) {
      int row = i * 32 + w * 8 + srow;
      gload_lds16(W + (size_t)(n0 + row) * DMODEL + k0 + cg * 8, &Bs[buf][(i * 256 + w * 64) * 8]);
    }
  };

  stage(0, 0);
  __syncthreads();

  for (int kt = 0; kt < 12; ++kt) {
    int cur = kt & 1;
    if (kt < 11) stage(kt + 1, cur ^ 1);
#pragma unroll
    for (int kk = 0; kk < 2; ++kk) {
      bf16x8 av[4], bv[2];
#pragma unroll
      for (int m = 0; m < 4; ++m) {
        int row = wm * 64 + m * 16 + c;
        av[m] = *(const bf16x8*)&As[cur][row * 64 + ((kk * 32 + g * 8) ^ ((row & 7) << 3))];
      }
#pragma unroll
      for (int n = 0; n < 2; ++n) {
        int row = wn * 32 + n * 16 + c;
        bv[n] = *(const bf16x8*)&Bs[cur][row * 64 + ((kk * 32 + g * 8) ^ ((row & 7) << 3))];
      }
#pragma unroll
      for (int m = 0; m < 4; ++m)
#pragma unroll
        for (int n = 0; n < 2; ++n)
          acc[m][n] = __builtin_amdgcn_mfma_f32_16x16x32_bf16(av[m], bv[n], acc[m][n], 0, 0, 0);
    }
    __syncthreads();
  }
  // epilogue: C/D layout col=lane&15, row=(lane>>4)*4+reg
#pragma unroll
  for (int n = 0; n < 2; ++n) {
    int gcol = n0 + wn * 32 + n * 16 + c;
    float bvv = bias[gcol];
#pragma unroll
    for (int m = 0; m < 4; ++m) {
      int grow0 = m0 + wm * 64 + m * 16 + g * 4;
#pragma unroll
      for (int r = 0; r < 4; ++r)
        out[(size_t)(grow0 + r) * DMODEL + gcol] = to_bf16((acc[m][n][r] + bvv) * osc);
    }
  }
}

// ---------------- V transpose: vh[(bh*2048+s')][64 d] -> vhT[(bh*64+d)][2048 s'] ----------------
__global__ __launch_bounds__(256) void transposeV(const u16* __restrict__ vh,
                                                  u16* __restrict__ vhT) {
  __shared__ u16 T[64][72];   // [d][s' local]
  int bh = blockIdx.y;        // 0..23
  int s0 = blockIdx.x * 64;
  int tid = threadIdx.x;
#pragma unroll
  for (int it = 0; it < 2; ++it) {
    int cch = it * 256 + tid;
    int r = cch >> 3, dc = (cch & 7) * 8;     // s'-row r, d-chunk dc
    us8 v = *(const us8*)(vh + ((size_t)bh * 2048 + s0 + r) * 64 + dc);
#pragma unroll
    for (int j = 0; j < 8; ++j) T[dc + j][r] = v[j];   // scatter-transpose into LDS
  }
  __syncthreads();
#pragma unroll
  for (int it = 0; it < 2; ++it) {
    int cch = it * 256 + tid;
    int d = cch >> 3, sc = (cch & 7) * 8;
    us8 v = *(const us8*)&T[d][sc];
    *(us8*)(vhT + ((size_t)bh * 64 + d) * 2048 + s0 + sc) = v;
  }
}

// ---------------- fused flash attention: swapped 32x32 QK^T, fixed-m softmax, KV-split=4 ----------------
// grid (16,12,8) remapped; per block 4 waves x 32 q-rows = 128 q, 512-key strip.
// Sequential 32-key half-tiles (one f32x16 score block live; VGPR 88).
// NO s_setprio: 4-wave barrier-synced lockstep — R14 showed the per-cluster prio
// toggling was serializing co-resident waves (T5/m190 lockstep effect, ~2.5x cost).
// Per-strip output NORMALIZED (O_s/l_s): strip0 -> f32 po0 (d_out), strips 1-3 -> bf16.
__global__ __launch_bounds__(256) void attn32(
    const u16* __restrict__ qh, const u16* __restrict__ kh, const u16* __restrict__ vt,
    const u64* __restrict__ mbt, float* __restrict__ po0, u16* __restrict__ po1,
    u16* __restrict__ po2, u16* __restrict__ po3, float* __restrict__ pl) {
  __shared__ u16 K0[4096], V0[4096], K1[4096], V1[4096];

  int tid = threadIdx.x, w = tid >> 6, l = tid & 63;
  int q = l & 31, hi = l >> 5;

  int lin = blockIdx.x + 16 * (blockIdx.y + 12 * blockIdx.z);
  int wid = (lin & 7) * 192 + (lin >> 3);           // 1536 % 8 == 0, bijective
  int qb = wid & 15;
  int rest = wid >> 4;
  int h = rest % 12;
  int z = rest / 12;                                // 0..7
  int strip = z & 3, b = z >> 2;
  int kbase = strip * 512;
  size_t hb = (size_t)(b * NHEAD + h) * SEQ * DK;
  int qrow = qb * 128 + w * 32 + q;

  // Q as B-operand: col=lane&31=q, k = (lane>>5)*8 + j within each 16-slice
  bf16x8 qf[4];
#pragma unroll
  for (int s = 0; s < 4; ++s)
    qf[s] = *(const bf16x8*)(qh + hb + (size_t)qrow * DK + s * 16 + hi * 8);

  f32x16 o0 = {}, o1 = {};
  float l_run = 0.f;

  // staging source pointers (per-lane, pre-swizzled)
  int idx0 = w * 64 + l;                 // chunk 0..255
  int r0s = idx0 >> 3;                   // source row 0..31
  int sc0 = ((idx0 & 7) ^ (r0s & 7)) * 8;
  const u16* kS = kh + hb + (size_t)(kbase + r0s) * DK + sc0;
  const u16* vS = vt + hb + (size_t)r0s * SEQ + kbase + sc0;
  const u64* mp = mbt + ((size_t)b * 32 + strip * 8) * SEQ + qrow;

  auto stage = [&](int t, u16* Kd, u16* Vd) {
    const u16* kp = kS + (size_t)t * (64 * DK);
    const u16* vp = vS + t * 64;
    gload_lds16(kp,            Kd + w * 512);
    gload_lds16(kp + 32 * DK,  Kd + 2048 + w * 512);
    gload_lds16(vp,            Vd + w * 512);
    gload_lds16(vp + 32 * SEQ, Vd + 2048 + w * 512);
  };

  // hoisted swizzled LDS read offsets (u16 units); rows q and q+32 share the slot
  int ofA[4];
#pragma unroll
  for (int s = 0; s < 4; ++s)
    ofA[s] = q * 64 + (((2 * s + hi) ^ (q & 7)) * 8);

  // one 32-key half-tile: QK^T -> exp/mask -> l partials -> pack -> PV
  auto computeHalf = [&](const u16* Kc, const u16* Vc, u32 mm, int kb) {
    const int roff = kb * 2048;          // K rows q+32 for the upper half
    f32x16 s = {};
#pragma unroll
    for (int ss = 0; ss < 4; ++ss) {
      bf16x8 kf = *(const bf16x8*)(Kc + ofA[ss] + roff);
      s = __builtin_amdgcn_mfma_f32_32x32x16_bf16(kf, qf[ss], s, 0, 0, 0);
    }

    // raw v_exp_f32 + 2-op mask; 4-chain partial row-sums feed l_run (VALU)
    float rs0 = 0.f, rs1 = 0.f, rs2 = 0.f, rs3 = 0.f;
#pragma unroll
    for (int r = 0; r < 16; ++r) {
      const int p = (r & 3) + 8 * (r >> 2);      // relative bit pos for this reg
      float e = fexp2(s[r]);
      int km = sext_bit(mm, p);                  // 0 / ~0
      e = __builtin_bit_cast(float, __builtin_bit_cast(int, e) & km);
      s[r] = e;
      if ((r & 3) == 0) rs0 += e;
      else if ((r & 3) == 1) rs1 += e;
      else if ((r & 3) == 2) rs2 += e;
      else rs3 += e;
    }
    l_run += (rs0 + rs1) + (rs2 + rs3);

    // pack P to bf16 A-frags; cross-half exchange via permlane32_swap.
    // (vdst=A, vsrc=B): A' = [A.row0|B.row0] (word0), B' = [A.row1|B.row1] (word2).
#pragma unroll
    for (int hf = 0; hf < 2; ++hf) {
      int ks = kb * 2 + hf;
      u32 A0 = cvt_pk_bf16(s[8 * hf + 0], s[8 * hf + 1]);
      u32 A1 = cvt_pk_bf16(s[8 * hf + 2], s[8 * hf + 3]);
      u32 B0 = cvt_pk_bf16(s[8 * hf + 4], s[8 * hf + 5]);
      u32 B1 = cvt_pk_bf16(s[8 * hf + 6], s[8 * hf + 7]);
      asm("v_permlane32_swap_b32 %0, %1" : "+v"(A0), "+v"(B0));
      asm("v_permlane32_swap_b32 %0, %1" : "+v"(A1), "+v"(B1));
      u32x4 fw;
      fw[0] = A0; fw[1] = A1; fw[2] = B0; fw[3] = B1;
      bf16x8 pa = __builtin_bit_cast(bf16x8, fw);
      bf16x8 v0 = *(const bf16x8*)(Vc + ofA[ks]);
      bf16x8 v1 = *(const bf16x8*)(Vc + ofA[ks] + 2048);
      o0 = __builtin_amdgcn_mfma_f32_32x32x16_bf16(pa, v0, o0, 0, 0, 0);
      o1 = __builtin_amdgcn_mfma_f32_32x32x16_bf16(pa, v1, o1, 0, 0, 0);
    }
  };

  auto compute = [&](const u16* Kc, const u16* Vc, u64 mcur) {
    computeHalf(Kc, Vc, (u32)(mcur >> (4 * hi)), 0);
    computeHalf(Kc, Vc, (u32)((mcur >> 32) >> (4 * hi)), 1);
  };

  // ---- software-pipelined main loop over 8 tiles, unroll-2 with named buffers ----
  stage(0, K0, V0);
  u64 mcur = mp[0];
  __syncthreads();

  for (int tt = 0; tt < 4; ++tt) {
    const int t0 = 2 * tt;
    u64 mnext = mp[(size_t)(t0 + 1) * SEQ];
    stage(t0 + 1, K1, V1);          // in flight across this compute
    compute(K0, V0, mcur);
    __syncthreads();                // drains stage(t0+1)
    mcur = mnext;
    if (tt < 3) {
      mnext = mp[(size_t)(t0 + 2) * SEQ];
      stage(t0 + 2, K0, V0);
    }
    compute(K1, V1, mcur);
    __syncthreads();
    mcur = mnext;
  }

  // ---- epilogue: cross-half l reduce; lane j holds l(row j&31); per-row via shfl
  l_run += __shfl_xor(l_run, 32);
  if (strip == 0) {
#pragma unroll
    for (int r = 0; r < 16; ++r) {
      int crow = (r & 3) + 8 * (r >> 2) + 4 * hi;
      float invl = __builtin_amdgcn_rcpf(__shfl(l_run, crow));
      int row = qb * 128 + w * 32 + crow;
      po0[hb + (size_t)row * DK + q]      = o0[r] * invl;
      po0[hb + (size_t)row * DK + 32 + q] = o1[r] * invl;
    }
  } else {
    u16* oo = (strip == 1) ? po1 : (strip == 2) ? po2 : po3;
#pragma unroll
    for (int r = 0; r < 16; ++r) {
      int crow = (r & 3) + 8 * (r >> 2) + 4 * hi;
      float invl = __builtin_amdgcn_rcpf(__shfl(l_run, crow));
      int row = qb * 128 + w * 32 + crow;
      oo[hb + (size_t)row * DK + q]      = to_bf16(o0[r] * invl);
      oo[hb + (size_t)row * DK + 32 + q] = to_bf16(o1[r] * invl);
    }
  }
  if (hi == 0)
    pl[(size_t)strip * BHS + (size_t)(b * NHEAD + h) * SEQ + qrow] = l_run;
}

// ---------------- combine the 4 normalized KV-strip partials (l-weighted avg) ----------------
__global__ __launch_bounds__(256) void combine_kernel(
    const float* __restrict__ po0, const u16* __restrict__ po1,
    const u16* __restrict__ po2, const u16* __restrict__ po3,
    const float* __restrict__ pl, float* __restrict__ out) {
  int i = blockIdx.x * 256 + threadIdx.x;     // vec4 index; grid covers BHS*16 exactly
  int row = i >> 4;
  float l0 = pl[row], l1 = pl[BHS + row], l2 = pl[2 * BHS + row], l3 = pl[3 * BHS + row];
  float inv = 1.f / (l0 + l1 + l2 + l3);
  f32x4 a = ((const f32x4*)po0)[i];
  us4 b1 = ((const us4*)po1)[i];
  us4 b2 = ((const us4*)po2)[i];
  us4 b3 = ((const us4*)po3)[i];
  f32x4 acc;
#pragma unroll
  for (int j = 0; j < 4; ++j)
    acc[j] = a[j] * l0 + bf16_to_f32(b1[j]) * l1 + bf16_to_f32(b2[j]) * l2 +
             bf16_to_f32(b3[j]) * l3;
  ((f32x4*)out)[i] = acc * inv;   // po0 == out: in-place per-element, safe
}

extern "C" void kernel_launch(void* const* d_in, const int* in_sizes, int n_in,
                              void* d_out, int out_size, void* d_ws, size_t ws_size,
                              hipStream_t stream) {
  const float* q    = (const float*)d_in[0];
  const float* k    = (const float*)d_in[1];
  const float* v    = (const float*)d_in[2];
  const int*   mask = (const int*)d_in[3];
  const float* Wq   = (const float*)d_in[4];
  const float* bq   = (const float*)d_in[5];
  const float* Wk   = (const float*)d_in[6];
  const float* bk   = (const float*)d_in[7];
  const float* Wv   = (const float*)d_in[8];
  const float* bv   = (const float*)d_in[9];

  char* ws = (char*)d_ws;
  const size_t szX = (size_t)MROWS * DMODEL * 2;   // 6291456 B
  const size_t szW = (size_t)DMODEL * DMODEL * 2;  // 1179648 B
  u16* xq  = (u16*)(ws);
  u16* xk  = (u16*)(ws + szX);
  u16* xv  = (u16*)(ws + 2 * szX);
  u16* wqb = (u16*)(ws + 3 * szX);
  u16* wkb = (u16*)(ws + 3 * szX + szW);
  u16* wvb = (u16*)(ws + 3 * szX + 2 * szW);
  u16* qh  = (u16*)(ws + 3 * szX + 3 * szW);
  u16* kh  = (u16*)(ws + 4 * szX + 3 * szW);
  u16* vh  = (u16*)(ws + 5 * szX + 3 * szW);       // linear [4096][768] == [bh][s'][d]
  u64* mb  = (u64*)(ws + 6 * szX + 3 * szW);       // 1 MB, [b][word][s]

  // dead-after-proj/transpose regions reused during attention:
  u16*   po1b = (u16*)(ws);                         // xq slot (6.29 MB, bf16 partial)
  u16*   po2b = (u16*)(ws + szX);                   // xk slot
  u16*   vhT  = (u16*)(ws + 2 * szX);               // xv slot (written by transposeV)
  float* pl   = (float*)(ws + 3 * szX);             // weights slot (4*BHS*4 = 786 KB)
  u16*   po3b = (u16*)(ws + 5 * szX + 3 * szW);     // vh slot (dead after transposeV)
  float* po0  = (float*)d_out;

  const int nbig = (MROWS * DMODEL) / 8;    // 393216
  const int nsmall = (DMODEL * DMODEL) / 8; // 73728

  cvt_pack<<<dim3(2048, 7), 256, 0, stream>>>(q, k, v, Wq, Wk, Wv, mask,
                                              xq, xk, xv, wqb, wkb, wvb, mb,
                                              nbig, nsmall);
  proj_gemm<<<dim3(384, 3), 256, 0, stream>>>(
      xq, xk, xv, wqb, wkb, wvb, bq, bk, bv, qh, kh, vh);
  transposeV<<<dim3(32, 24), 256, 0, stream>>>(vh, vhT);
  attn32<<<dim3(16, 12, 8), 256, 0, stream>>>(qh, kh, vhT, mb, po0, po1b, po2b, po3b, pl);
  combine_kernel<<<(BHS * 16) / 256, 256, 0, stream>>>(po0, po1b, po2b, po3b, pl, (float*)d_out);
}